// Round 2
// baseline (1076.520 us; speedup 1.0000x reference)
//
#include <hip/hip_runtime.h>

// Problem constants
#define BB   4
#define CC   256
#define HWD  64
#define NPIX 4096            // 64*64
#define PB   1048576         // per-batch elements: NPIX*CC

typedef __attribute__((ext_vector_type(8))) short bf16x8;
typedef __attribute__((ext_vector_type(4))) float f32x4;
typedef __attribute__((ext_vector_type(4))) unsigned short u16x4;

__device__ __forceinline__ unsigned short f2b(float f) {
  union { float f; unsigned u; } v; v.f = f;
  unsigned r = v.u + 0x7fffu + ((v.u >> 16) & 1u);
  return (unsigned short)(r >> 16);
}
__device__ __forceinline__ float b2f(unsigned short h) {
  union { unsigned u; float f; } v; v.u = ((unsigned)h) << 16;
  return v.f;
}
__device__ __forceinline__ f32x4 mfma16(bf16x8 a, bf16x8 b, f32x4 c) {
  return __builtin_amdgcn_mfma_f32_16x16x32_bf16(a, b, c, 0, 0, 0);
}
// reflect-pad(1) pixel remap for 64x64 image
__device__ __forceinline__ int remap_px(int n, int dh, int dw) {
  int h = (n >> 6) + dh;
  int w = (n & 63) + dw;
  h = h < 0 ? 1 : (h > 63 ? 62 : h);
  w = w < 0 ? 1 : (w > 63 ? 62 : w);
  return (h << 6) | w;
}

// ---------------- weight repack ----------------
__global__ void repack_w1x1_k(const float* __restrict__ tw, const float* __restrict__ pw,
                              const float* __restrict__ gw, const float* __restrict__ Ww,
                              unsigned short* __restrict__ dst) {
  int i = blockIdx.x * 256 + threadIdx.x;          // 65536 total
  dst[i]           = f2b(tw[i]);
  dst[65536 + i]   = f2b(pw[i]);
  dst[131072 + i]  = f2b(gw[i]);
  dst[196608 + i]  = f2b(Ww[i]);
}

__global__ void repack_res_k(const float* __restrict__ w1, const float* __restrict__ w2,
                             unsigned short* __restrict__ wk) {
  int idx = blockIdx.x * 256 + threadIdx.x;        // 3*256*256*9 = 1769472 total
  if (idx >= 1769472) return;
  int t = idx % 9;
  int rest = idx / 9;                              // (i*256+o)*256+c
  int c = rest & 255;
  int o = (rest >> 8) & 255;
  int i = rest >> 16;
  size_t d = (size_t)t * 65536 + o * 256 + c;      // [t][o][c] within one conv
  wk[(size_t)(2 * i)     * 589824 + d] = f2b(w1[idx]);
  wk[(size_t)(2 * i + 1) * 589824 + d] = f2b(w2[idx]);
}

// ---------------- mask prep ----------------
__global__ void prep_mask_k(const float* __restrict__ mask, float* __restrict__ m) {
  int idx = blockIdx.x * 256 + threadIdx.x;        // B*4096
  if (idx >= BB * NPIX) return;
  int b = idx >> 12, n = idx & 4095;
  int h = n >> 6, w = n & 63;
  const float* M = mask + b * 1024;
  float sh = 0.5f * h - 0.25f, sw = 0.5f * w - 0.25f;
  int h0 = (int)floorf(sh), w0 = (int)floorf(sw);
  float th = sh - h0, tw = sw - w0;
  int h0c = min(max(h0, 0), 31), h1c = min(max(h0 + 1, 0), 31);
  int w0c = min(max(w0, 0), 31), w1c = min(max(w0 + 1, 0), 31);
  float v = (1.f - th) * ((1.f - tw) * M[h0c * 32 + w0c] + tw * M[h0c * 32 + w1c])
          +        th  * ((1.f - tw) * M[h1c * 32 + w0c] + tw * M[h1c * 32 + w1c]);
  float inv = v > 0.f ? 0.f : 1.f;                 // 1 - where(v>0,1,v), v in {0..1}
  float tmp = 1.f - M[(h >> 1) * 32 + (w >> 1)];   // nearest upsample of (1-mask)
  m[idx] = inv * tmp;                              // binary {0,1}
}

// ---------------- x transpose: [B,C,N] f32 -> [B,N,C] bf16 ----------------
__global__ void transpose_x_k(const float* __restrict__ x, unsigned short* __restrict__ xT) {
  __shared__ float T[64][65];
  int b = blockIdx.z;
  int n0 = blockIdx.x * 64, c0 = blockIdx.y * 64;
  int tx = threadIdx.x, ty = threadIdx.y;
  const float* xb = x + (size_t)b * PB;
  #pragma unroll
  for (int i = 0; i < 16; ++i) {
    int cl = ty + i * 4;
    T[cl][tx] = xb[(size_t)(c0 + cl) * NPIX + n0 + tx];
  }
  __syncthreads();
  unsigned short* ob = xT + (size_t)b * PB;
  #pragma unroll
  for (int i = 0; i < 16; ++i) {
    int nl = ty + i * 4;
    ob[(size_t)(n0 + nl) * CC + c0 + tx] = f2b(T[tx][nl]);
  }
}

// ---------------- generic bt-GEMM: C[M,N] = A[M,K] * B[N,K]^T ----------------
// EPI 0: bf16 row-major out[row*N+col] (+biasRow[row] +biasCol[col])
// EPI 1: bf16 transposed out[col*M+row] (no bias needed)
// EPI 2: f32 + bf16 transposed (+biasRow)
template <int EPI, bool CONV>
__launch_bounds__(256, 2)
__global__ void gemm_bt(const unsigned short* __restrict__ A,
                        const unsigned short* __restrict__ Bm,
                        const float* __restrict__ biasRow,
                        const float* __restrict__ biasCol,
                        float* __restrict__ outF,
                        unsigned short* __restrict__ outB,
                        int M, int N, int K,
                        long sAb, long sBb, long sOb) {
  constexpr int TM = 128, TN = 64, BK = 32;
  int b = blockIdx.z;
  const unsigned short* Ab = A + (size_t)b * sAb;
  const unsigned short* Bb = Bm + (size_t)b * sBb;
  int m0 = blockIdx.y * TM, n0 = blockIdx.x * TN;
  int tid = threadIdx.x, lane = tid & 63, wid = tid >> 6;
  int wm = wid >> 1, wn = wid & 1;
  int r16 = lane & 15, g4 = lane >> 4;
  __shared__ __align__(16) unsigned short As[TM * BK];
  __shared__ __align__(16) unsigned short Bs[TN * BK];
  f32x4 acc[4][2] = {};
  int arow0 = tid >> 2, acol = (tid & 3) * 8;
  int arow1 = arow0 + 64;
  int brow = tid >> 2;
  const int nslice = CONV ? 9 : 1;
  for (int t = 0; t < nslice; ++t) {
    const unsigned short* Asl = Ab + (size_t)t * M * K;
    int bsrc = n0 + brow;
    if (CONV) bsrc = remap_px(n0 + brow, t / 3 - 1, t % 3 - 1);
    const unsigned short* Ap0 = Asl + (size_t)(m0 + arow0) * K + acol;
    const unsigned short* Ap1 = Asl + (size_t)(m0 + arow1) * K + acol;
    const unsigned short* Bp  = Bb + (size_t)bsrc * K + acol;
    for (int k0 = 0; k0 < K; k0 += BK) {
      bf16x8 a0 = *(const bf16x8*)(Ap0 + k0);
      bf16x8 a1 = *(const bf16x8*)(Ap1 + k0);
      bf16x8 b0 = *(const bf16x8*)(Bp + k0);
      __syncthreads();
      *(bf16x8*)&As[arow0 * BK + acol] = a0;
      *(bf16x8*)&As[arow1 * BK + acol] = a1;
      *(bf16x8*)&Bs[brow * BK + acol]  = b0;
      __syncthreads();
      bf16x8 af[4], bfv[2];
      #pragma unroll
      for (int i = 0; i < 4; ++i) af[i] = *(const bf16x8*)&As[(wm * 64 + i * 16 + r16) * BK + 8 * g4];
      #pragma unroll
      for (int j = 0; j < 2; ++j) bfv[j] = *(const bf16x8*)&Bs[(wn * 32 + j * 16 + r16) * BK + 8 * g4];
      #pragma unroll
      for (int i = 0; i < 4; ++i)
        #pragma unroll
        for (int j = 0; j < 2; ++j)
          acc[i][j] = mfma16(af[i], bfv[j], acc[i][j]);
    }
  }
  unsigned short* outBb = outB + (size_t)b * sOb;
  #pragma unroll
  for (int i = 0; i < 4; ++i) {
    int row = m0 + wm * 64 + i * 16 + g4 * 4;
    #pragma unroll
    for (int j = 0; j < 2; ++j) {
      int col = n0 + wn * 32 + j * 16 + r16;
      f32x4 v = acc[i][j];
      if constexpr (EPI == 0) {
        float bc = biasCol ? biasCol[col] : 0.f;
        #pragma unroll
        for (int r = 0; r < 4; ++r) {
          float f = v[r] + bc + (biasRow ? biasRow[row + r] : 0.f);
          outBb[(size_t)(row + r) * N + col] = f2b(f);
        }
      } else {
        if (biasRow) {
          v[0] += biasRow[row]; v[1] += biasRow[row + 1];
          v[2] += biasRow[row + 2]; v[3] += biasRow[row + 3];
        }
        size_t o = (size_t)col * M + row;
        if constexpr (EPI == 2) {
          float* outFb = outF + (size_t)b * sOb;
          *(f32x4*)&outFb[o] = v;
        }
        u16x4 pk;
        pk[0] = f2b(v[0]); pk[1] = f2b(v[1]); pk[2] = f2b(v[2]); pk[3] = f2b(v[3]);
        *(u16x4*)&outBb[o] = pk;
      }
    }
  }
}

// ---------------- fused masked attention ----------------
// theta,phi: [B,N,C] bf16 (row per pixel); gv: [B,C,N] bf16 (V^T); m: [B,N] f32 binary
// y: [B,N,C] bf16 ; y[n] = sum_k exp(s_nk - max) * m_k * V[k] / sum_k exp * m_k   (0 if empty)
__launch_bounds__(128)
__global__ void attn_k(const unsigned short* __restrict__ theta,
                       const unsigned short* __restrict__ phi,
                       const unsigned short* __restrict__ gv,
                       const float* __restrict__ mm,
                       unsigned short* __restrict__ y) {
  int b = blockIdx.y;
  int q0 = blockIdx.x * 32;
  int tid = threadIdx.x, lane = tid & 63, wid = tid >> 6;
  int r16 = lane & 15, g4 = lane >> 4;
  const unsigned short* th = theta + (size_t)b * PB;
  const unsigned short* ph = phi + (size_t)b * PB;
  const unsigned short* gb = gv + (size_t)b * PB;
  __shared__ float ml[NPIX];
  __shared__ __align__(16) unsigned short Plds[2][16][80];
  for (int i = tid; i < NPIX; i += 128) ml[i] = mm[b * NPIX + i];
  __syncthreads();
  int qrow = q0 + wid * 16 + r16;
  bf16x8 aq[8];
  #pragma unroll
  for (int ks = 0; ks < 8; ++ks)
    aq[ks] = *(const bf16x8*)(th + (size_t)qrow * CC + ks * 32 + 8 * g4);
  f32x4 O[16];
  #pragma unroll
  for (int cf = 0; cf < 16; ++cf) { O[cf][0] = 0.f; O[cf][1] = 0.f; O[cf][2] = 0.f; O[cf][3] = 0.f; }
  float mrow[4] = {-1e30f, -1e30f, -1e30f, -1e30f};
  float lrow[4] = {0.f, 0.f, 0.f, 0.f};
  for (int k0 = 0; k0 < NPIX; k0 += 64) {
    f32x4 S[4];
    #pragma unroll
    for (int f = 0; f < 4; ++f) { S[f][0] = 0.f; S[f][1] = 0.f; S[f][2] = 0.f; S[f][3] = 0.f; }
    #pragma unroll
    for (int ks = 0; ks < 8; ++ks) {
      #pragma unroll
      for (int f = 0; f < 4; ++f) {
        bf16x8 bk = *(const bf16x8*)(ph + (size_t)(k0 + f * 16 + r16) * CC + ks * 32 + 8 * g4);
        S[f] = mfma16(aq[ks], bk, S[f]);
      }
    }
    float mk[4];
    #pragma unroll
    for (int f = 0; f < 4; ++f) mk[f] = ml[k0 + f * 16 + r16];
    float scr[4];
    #pragma unroll
    for (int r = 0; r < 4; ++r) {
      float v = -1e30f;
      #pragma unroll
      for (int f = 0; f < 4; ++f) v = fmaxf(v, mk[f] > 0.f ? S[f][r] : -1e30f);
      v = fmaxf(v, __shfl_xor(v, 1));
      v = fmaxf(v, __shfl_xor(v, 2));
      v = fmaxf(v, __shfl_xor(v, 4));
      v = fmaxf(v, __shfl_xor(v, 8));
      float nm = fmaxf(mrow[r], v);
      scr[r] = __expf(mrow[r] - nm);
      mrow[r] = nm;
      lrow[r] *= scr[r];
    }
    float ps[4][4];
    float rsum[4] = {0.f, 0.f, 0.f, 0.f};
    #pragma unroll
    for (int f = 0; f < 4; ++f)
      #pragma unroll
      for (int r = 0; r < 4; ++r) {
        float p = mk[f] > 0.f ? __expf(S[f][r] - mrow[r]) : 0.f;
        ps[f][r] = p;
        rsum[r] += p;
      }
    #pragma unroll
    for (int r = 0; r < 4; ++r) {
      float s = rsum[r];
      s += __shfl_xor(s, 1);
      s += __shfl_xor(s, 2);
      s += __shfl_xor(s, 4);
      s += __shfl_xor(s, 8);
      lrow[r] += s;
    }
    #pragma unroll
    for (int cf = 0; cf < 16; ++cf) {
      O[cf][0] *= scr[0]; O[cf][1] *= scr[1]; O[cf][2] *= scr[2]; O[cf][3] *= scr[3];
    }
    #pragma unroll
    for (int f = 0; f < 4; ++f)
      #pragma unroll
      for (int r = 0; r < 4; ++r)
        Plds[wid][g4 * 4 + r][f * 16 + r16] = f2b(ps[f][r]);
    #pragma unroll
    for (int ks2 = 0; ks2 < 2; ++ks2) {
      bf16x8 ap = *(const bf16x8*)&Plds[wid][r16][ks2 * 32 + 8 * g4];
      #pragma unroll
      for (int cf = 0; cf < 16; ++cf) {
        bf16x8 bv = *(const bf16x8*)(gb + (size_t)(cf * 16 + r16) * NPIX + k0 + ks2 * 32 + 8 * g4);
        O[cf] = mfma16(ap, bv, O[cf]);
      }
    }
  }
  float li[4];
  #pragma unroll
  for (int r = 0; r < 4; ++r) li[r] = lrow[r] > 1e-30f ? 1.f / lrow[r] : 0.f;
  unsigned short* yb = y + (size_t)b * PB;
  #pragma unroll
  for (int cf = 0; cf < 16; ++cf)
    #pragma unroll
    for (int r = 0; r < 4; ++r)
      yb[(size_t)(q0 + wid * 16 + g4 * 4 + r) * CC + cf * 16 + r16] = f2b(O[cf][r] * li[r]);
}

// ---------------- instance-norm stats ----------------
__global__ void in_stats_k(const unsigned short* __restrict__ v,
                           float* __restrict__ psum, float* __restrict__ psumsq) {
  int p = blockIdx.x;          // 32 pixel-chunks of 128
  int b = blockIdx.y;
  int c = threadIdx.x;
  const unsigned short* base = v + (size_t)b * PB + (size_t)p * 128 * CC + c;
  float s = 0.f, s2 = 0.f;
  for (int n = 0; n < 128; ++n) {
    float f = b2f(base[n * CC]);
    s += f; s2 += f * f;
  }
  int o = (p * BB + b) * CC + c;
  psum[o] = s; psumsq[o] = s2;
}

__global__ void in_finalize_k(const float* __restrict__ psum, const float* __restrict__ psumsq,
                              float* __restrict__ mu, float* __restrict__ rs) {
  int bc = blockIdx.x * 256 + threadIdx.x;   // 1024
  int b = bc >> 8, c = bc & 255;
  float s = 0.f, s2 = 0.f;
  for (int p = 0; p < 32; ++p) {
    s  += psum[(p * BB + b) * CC + c];
    s2 += psumsq[(p * BB + b) * CC + c];
  }
  float m_ = s * (1.f / 4096.f);
  float var = s2 * (1.f / 4096.f) - m_ * m_;
  var = var > 0.f ? var : 0.f;
  mu[bc] = m_;
  rs[bc] = rsqrtf(var + 1e-5f);
}

// ---------------- IN+ReLU apply ----------------
__global__ void normrelu_k(const unsigned short* __restrict__ src,
                           const float* __restrict__ mu, const float* __restrict__ rs,
                           unsigned short* __restrict__ dst) {
  size_t idx = (size_t)blockIdx.x * 256 + threadIdx.x;
  size_t e = idx * 8;
  if (e >= (size_t)BB * PB) return;
  int c = (int)(e & 255);
  int b = (int)(e >> 20);
  const float* mup = mu + b * 256 + c;
  const float* rsp = rs + b * 256 + c;
  bf16x8 v = *(const bf16x8*)(src + e);
  bf16x8 ov;
  #pragma unroll
  for (int j = 0; j < 8; ++j) {
    float f = (b2f((unsigned short)v[j]) - mup[j]) * rsp[j];
    ov[j] = (short)f2b(f > 0.f ? f : 0.f);
  }
  *(bf16x8*)(dst + e) = ov;
}

// ---------------- residual += IN(conv2), keep f32 + bf16 ----------------
__global__ void resupdate_k(const unsigned short* __restrict__ c2,
                            const float* __restrict__ mu, const float* __restrict__ rs,
                            float* __restrict__ r, unsigned short* __restrict__ rb) {
  size_t idx = (size_t)blockIdx.x * 256 + threadIdx.x;
  size_t e = idx * 8;
  if (e >= (size_t)BB * PB) return;
  int c = (int)(e & 255);
  int b = (int)(e >> 20);
  const float* mup = mu + b * 256 + c;
  const float* rsp = rs + b * 256 + c;
  bf16x8 v = *(const bf16x8*)(c2 + e);
  bf16x8 ov;
  #pragma unroll
  for (int j = 0; j < 8; ++j) {
    float f = r[e + j] + (b2f((unsigned short)v[j]) - mup[j]) * rsp[j];
    r[e + j] = f;
    ov[j] = (short)f2b(f);
  }
  *(bf16x8*)(rb + e) = ov;
}

// ---------------- final blend: out[b,c,n] = m*x + (1-m)*r3[b,n,c] ----------------
__global__ void final_blend_k(const float* __restrict__ x, const float* __restrict__ r,
                              const float* __restrict__ m, float* __restrict__ out) {
  __shared__ float T[64][65];
  int b = blockIdx.z;
  int n0 = blockIdx.x * 64, c0 = blockIdx.y * 64;
  int tx = threadIdx.x, ty = threadIdx.y;
  #pragma unroll
  for (int i = 0; i < 16; ++i) {
    int nl = ty + i * 4;
    T[nl][tx] = r[(size_t)b * PB + (size_t)(n0 + nl) * CC + c0 + tx];
  }
  __syncthreads();
  #pragma unroll
  for (int i = 0; i < 16; ++i) {
    int cl = ty + i * 4;
    int cg = c0 + cl, ng = n0 + tx;
    float mv = m[b * NPIX + ng];
    float xv = x[(size_t)b * PB + (size_t)cg * NPIX + ng];
    out[(size_t)b * PB + (size_t)cg * NPIX + ng] = mv * xv + (1.f - mv) * T[tx][cl];
  }
}

// ---------------- workspace layout (bytes) ----------------
#define OFF_M    0UL
#define OFF_XT   65536UL        // xT bf16 [B,N,C]; later reused as y
#define OFF_TH   8454144UL      // theta bf16 [B,N,C]; later reused as cbuf (c1/c2)
#define OFF_PH   16842752UL     // phi bf16 [B,N,C]; later reused as hbuf
#define OFF_G    25231360UL     // g bf16 [B,C,N]; later reused as rb
#define OFF_R    33619968UL     // residual f32 [B,N,C]
#define OFF_W1   50397184UL     // 1x1 weights bf16: theta, phi, g, W (65536 each)
#define OFF_WK   50921472UL     // res conv weights bf16 [6][9][256][256]
#define OFF_MU   57999360UL
#define OFF_RS   58003456UL
#define OFF_PS   58007552UL
#define OFF_PS2  58138624UL

extern "C" void kernel_launch(void* const* d_in, const int* in_sizes, int n_in,
                              void* d_out, int out_size, void* d_ws, size_t ws_size,
                              hipStream_t stream) {
  const float* x       = (const float*)d_in[0];
  const float* maskp   = (const float*)d_in[1];
  const float* g_w     = (const float*)d_in[2];
  const float* g_b     = (const float*)d_in[3];
  const float* theta_w = (const float*)d_in[4];
  const float* theta_b = (const float*)d_in[5];
  const float* phi_w   = (const float*)d_in[6];
  const float* phi_b   = (const float*)d_in[7];
  const float* W_w     = (const float*)d_in[8];
  const float* W_b     = (const float*)d_in[9];
  const float* res_w1  = (const float*)d_in[10];
  const float* res_w2  = (const float*)d_in[12];
  float* out = (float*)d_out;
  char* ws = (char*)d_ws;

  float*          mbuf = (float*)(ws + OFF_M);
  unsigned short* xT   = (unsigned short*)(ws + OFF_XT);
  unsigned short* ybuf = (unsigned short*)(ws + OFF_XT);   // alias (xT dead after g-gemm)
  unsigned short* thb  = (unsigned short*)(ws + OFF_TH);
  unsigned short* cbuf = (unsigned short*)(ws + OFF_TH);   // alias (theta dead after attn)
  unsigned short* phb  = (unsigned short*)(ws + OFF_PH);
  unsigned short* hbuf = (unsigned short*)(ws + OFF_PH);   // alias (phi dead after attn)
  unsigned short* gbuf = (unsigned short*)(ws + OFF_G);
  unsigned short* rb   = (unsigned short*)(ws + OFF_G);    // alias (g dead after attn)
  float*          rbuf = (float*)(ws + OFF_R);
  unsigned short* thw  = (unsigned short*)(ws + OFF_W1);
  unsigned short* phw  = (unsigned short*)(ws + OFF_W1 + 131072);
  unsigned short* gww  = (unsigned short*)(ws + OFF_W1 + 262144);
  unsigned short* Www  = (unsigned short*)(ws + OFF_W1 + 393216);
  unsigned short* wkres= (unsigned short*)(ws + OFF_WK);
  float*          mu   = (float*)(ws + OFF_MU);
  float*          rs   = (float*)(ws + OFF_RS);
  float*          psum = (float*)(ws + OFF_PS);
  float*          psq  = (float*)(ws + OFF_PS2);

  // weight repacks + mask + x transpose
  repack_w1x1_k<<<256, 256, 0, stream>>>(theta_w, phi_w, g_w, W_w, thw);
  repack_res_k<<<6912, 256, 0, stream>>>(res_w1, res_w2, wkres);
  prep_mask_k<<<64, 256, 0, stream>>>(maskp, mbuf);
  transpose_x_k<<<dim3(64, 4, 4), dim3(64, 4), 0, stream>>>(x, xT);

  // theta = xT @ theta_w^T + b  -> [B,N,C]
  gemm_bt<0, false><<<dim3(4, 32, 4), 256, 0, stream>>>(
      xT, thw, nullptr, theta_b, nullptr, thb, 4096, 256, 256, (long)PB, 0L, (long)PB);
  // phi = xT @ phi_w^T + b -> [B,N,C]
  gemm_bt<0, false><<<dim3(4, 32, 4), 256, 0, stream>>>(
      xT, phw, nullptr, phi_b, nullptr, phb, 4096, 256, 256, (long)PB, 0L, (long)PB);
  // g = g_w @ xT^T + b -> [B,C,N]
  gemm_bt<0, false><<<dim3(64, 2, 4), 256, 0, stream>>>(
      gww, xT, g_b, nullptr, nullptr, gbuf, 256, 4096, 256, 0L, (long)PB, (long)PB);

  // attention -> y [B,N,C]
  attn_k<<<dim3(128, 4), 128, 0, stream>>>(thb, phb, gbuf, mbuf, ybuf);

  // W_y = W_w @ y^T + W_b -> residual f32 [B,N,C] + bf16 copy
  gemm_bt<2, false><<<dim3(64, 2, 4), 256, 0, stream>>>(
      Www, ybuf, W_b, nullptr, rbuf, rb, 256, 4096, 256, 0L, (long)PB, (long)PB);

  // 3 residual blocks
  for (int i = 0; i < 3; ++i) {
    gemm_bt<1, true><<<dim3(64, 2, 4), 256, 0, stream>>>(
        wkres + (size_t)(2 * i) * 589824, rb, nullptr, nullptr, nullptr, cbuf,
        256, 4096, 256, 0L, (long)PB, (long)PB);
    in_stats_k<<<dim3(32, 4), 256, 0, stream>>>(cbuf, psum, psq);
    in_finalize_k<<<4, 256, 0, stream>>>(psum, psq, mu, rs);
    normrelu_k<<<2048, 256, 0, stream>>>(cbuf, mu, rs, hbuf);
    gemm_bt<1, true><<<dim3(64, 2, 4), 256, 0, stream>>>(
        wkres + (size_t)(2 * i + 1) * 589824, hbuf, nullptr, nullptr, nullptr, cbuf,
        256, 4096, 256, 0L, (long)PB, (long)PB);
    in_stats_k<<<dim3(32, 4), 256, 0, stream>>>(cbuf, psum, psq);
    in_finalize_k<<<4, 256, 0, stream>>>(psum, psq, mu, rs);
    resupdate_k<<<2048, 256, 0, stream>>>(cbuf, mu, rs, rbuf, rb);
  }

  // final blend + transpose to [B,C,H,W]
  final_blend_k<<<dim3(64, 4, 4), dim3(64, 4), 0, stream>>>(x, rbuf, mbuf, out);
}

// Round 3
// 657.594 us; speedup vs baseline: 1.6371x; 1.6371x over previous
//
#include <hip/hip_runtime.h>

// Problem constants
#define BB   4
#define CC   256
#define HWD  64
#define NPIX 4096            // 64*64
#define PB   1048576         // per-batch elements: NPIX*CC

typedef __attribute__((ext_vector_type(8))) short bf16x8;
typedef __attribute__((ext_vector_type(4))) float f32x4;
typedef __attribute__((ext_vector_type(4))) unsigned short u16x4;

__device__ __forceinline__ unsigned short f2b(float f) {
  union { float f; unsigned u; } v; v.f = f;
  unsigned r = v.u + 0x7fffu + ((v.u >> 16) & 1u);
  return (unsigned short)(r >> 16);
}
__device__ __forceinline__ float b2f(unsigned short h) {
  union { unsigned u; float f; } v; v.u = ((unsigned)h) << 16;
  return v.f;
}
__device__ __forceinline__ f32x4 mfma16(bf16x8 a, bf16x8 b, f32x4 c) {
  return __builtin_amdgcn_mfma_f32_16x16x32_bf16(a, b, c, 0, 0, 0);
}
// reflect-pad(1) pixel remap for 64x64 image
__device__ __forceinline__ int remap_px(int n, int dh, int dw) {
  int h = (n >> 6) + dh;
  int w = (n & 63) + dw;
  h = h < 0 ? 1 : (h > 63 ? 62 : h);
  w = w < 0 ? 1 : (w > 63 ? 62 : w);
  return (h << 6) | w;
}

// ---------------- weight repack ----------------
__global__ void repack_w1x1_k(const float* __restrict__ tw, const float* __restrict__ pw,
                              const float* __restrict__ gw, const float* __restrict__ Ww,
                              unsigned short* __restrict__ dst) {
  int i = blockIdx.x * 256 + threadIdx.x;          // 65536 total
  dst[i]           = f2b(tw[i]);
  dst[65536 + i]   = f2b(pw[i]);
  dst[131072 + i]  = f2b(gw[i]);
  dst[196608 + i]  = f2b(Ww[i]);
}

__global__ void repack_res_k(const float* __restrict__ w1, const float* __restrict__ w2,
                             unsigned short* __restrict__ wk) {
  int idx = blockIdx.x * 256 + threadIdx.x;        // 3*256*256*9 = 1769472 total
  if (idx >= 1769472) return;
  int t = idx % 9;
  int rest = idx / 9;                              // (i*256+o)*256+c
  int c = rest & 255;
  int o = (rest >> 8) & 255;
  int i = rest >> 16;
  size_t d = (size_t)t * 65536 + o * 256 + c;      // [t][o][c] within one conv
  wk[(size_t)(2 * i)     * 589824 + d] = f2b(w1[idx]);
  wk[(size_t)(2 * i + 1) * 589824 + d] = f2b(w2[idx]);
}

// ---------------- mask prep ----------------
__global__ void prep_mask_k(const float* __restrict__ mask, float* __restrict__ m) {
  int idx = blockIdx.x * 256 + threadIdx.x;        // B*4096
  if (idx >= BB * NPIX) return;
  int b = idx >> 12, n = idx & 4095;
  int h = n >> 6, w = n & 63;
  const float* M = mask + b * 1024;
  float sh = 0.5f * h - 0.25f, sw = 0.5f * w - 0.25f;
  int h0 = (int)floorf(sh), w0 = (int)floorf(sw);
  float th = sh - h0, tw = sw - w0;
  int h0c = min(max(h0, 0), 31), h1c = min(max(h0 + 1, 0), 31);
  int w0c = min(max(w0, 0), 31), w1c = min(max(w0 + 1, 0), 31);
  float v = (1.f - th) * ((1.f - tw) * M[h0c * 32 + w0c] + tw * M[h0c * 32 + w1c])
          +        th  * ((1.f - tw) * M[h1c * 32 + w0c] + tw * M[h1c * 32 + w1c]);
  float inv = v > 0.f ? 0.f : 1.f;                 // 1 - where(v>0,1,v), v in {0..1}
  float tmp = 1.f - M[(h >> 1) * 32 + (w >> 1)];   // nearest upsample of (1-mask)
  m[idx] = inv * tmp;                              // binary {0,1}
}

// ---------------- x transpose: [B,C,N] f32 -> [B,N,C] bf16 ----------------
__global__ void transpose_x_k(const float* __restrict__ x, unsigned short* __restrict__ xT) {
  __shared__ float T[64][65];
  int b = blockIdx.z;
  int n0 = blockIdx.x * 64, c0 = blockIdx.y * 64;
  int tx = threadIdx.x, ty = threadIdx.y;
  const float* xb = x + (size_t)b * PB;
  #pragma unroll
  for (int i = 0; i < 16; ++i) {
    int cl = ty + i * 4;
    T[cl][tx] = xb[(size_t)(c0 + cl) * NPIX + n0 + tx];
  }
  __syncthreads();
  unsigned short* ob = xT + (size_t)b * PB;
  #pragma unroll
  for (int i = 0; i < 16; ++i) {
    int nl = ty + i * 4;
    ob[(size_t)(n0 + nl) * CC + c0 + tx] = f2b(T[tx][nl]);
  }
}

// ---------------- generic bt-GEMM: C[M,N] = A[M,K] * B[N,K]^T ----------------
// EPI 0: bf16 row-major out[row*N+col] (+biasRow[row] +biasCol[col])
// EPI 1: bf16 transposed out[col*M+row] (no bias needed)
// EPI 2: f32 + bf16 transposed (+biasRow)
template <int EPI, bool CONV>
__launch_bounds__(256, 2)
__global__ void gemm_bt(const unsigned short* __restrict__ A,
                        const unsigned short* __restrict__ Bm,
                        const float* __restrict__ biasRow,
                        const float* __restrict__ biasCol,
                        float* __restrict__ outF,
                        unsigned short* __restrict__ outB,
                        int M, int N, int K,
                        long sAb, long sBb, long sOb) {
  constexpr int TM = 128, TN = 64, BK = 32;
  int b = blockIdx.z;
  const unsigned short* Ab = A + (size_t)b * sAb;
  const unsigned short* Bb = Bm + (size_t)b * sBb;
  int m0 = blockIdx.y * TM, n0 = blockIdx.x * TN;
  int tid = threadIdx.x, lane = tid & 63, wid = tid >> 6;
  int wm = wid >> 1, wn = wid & 1;
  int r16 = lane & 15, g4 = lane >> 4;
  __shared__ __align__(16) unsigned short As[TM * BK];
  __shared__ __align__(16) unsigned short Bs[TN * BK];
  f32x4 acc[4][2] = {};
  int arow0 = tid >> 2, acol = (tid & 3) * 8;
  int arow1 = arow0 + 64;
  int brow = tid >> 2;
  const int nslice = CONV ? 9 : 1;
  for (int t = 0; t < nslice; ++t) {
    const unsigned short* Asl = Ab + (size_t)t * M * K;
    int bsrc = n0 + brow;
    if (CONV) bsrc = remap_px(n0 + brow, t / 3 - 1, t % 3 - 1);
    const unsigned short* Ap0 = Asl + (size_t)(m0 + arow0) * K + acol;
    const unsigned short* Ap1 = Asl + (size_t)(m0 + arow1) * K + acol;
    const unsigned short* Bp  = Bb + (size_t)bsrc * K + acol;
    for (int k0 = 0; k0 < K; k0 += BK) {
      bf16x8 a0 = *(const bf16x8*)(Ap0 + k0);
      bf16x8 a1 = *(const bf16x8*)(Ap1 + k0);
      bf16x8 b0 = *(const bf16x8*)(Bp + k0);
      __syncthreads();
      *(bf16x8*)&As[arow0 * BK + acol] = a0;
      *(bf16x8*)&As[arow1 * BK + acol] = a1;
      *(bf16x8*)&Bs[brow * BK + acol]  = b0;
      __syncthreads();
      bf16x8 af[4], bfv[2];
      #pragma unroll
      for (int i = 0; i < 4; ++i) af[i] = *(const bf16x8*)&As[(wm * 64 + i * 16 + r16) * BK + 8 * g4];
      #pragma unroll
      for (int j = 0; j < 2; ++j) bfv[j] = *(const bf16x8*)&Bs[(wn * 32 + j * 16 + r16) * BK + 8 * g4];
      #pragma unroll
      for (int i = 0; i < 4; ++i)
        #pragma unroll
        for (int j = 0; j < 2; ++j)
          acc[i][j] = mfma16(af[i], bfv[j], acc[i][j]);
    }
  }
  unsigned short* outBb = outB + (size_t)b * sOb;
  #pragma unroll
  for (int i = 0; i < 4; ++i) {
    int row = m0 + wm * 64 + i * 16 + g4 * 4;
    #pragma unroll
    for (int j = 0; j < 2; ++j) {
      int col = n0 + wn * 32 + j * 16 + r16;
      f32x4 v = acc[i][j];
      if constexpr (EPI == 0) {
        float bc = biasCol ? biasCol[col] : 0.f;
        #pragma unroll
        for (int r = 0; r < 4; ++r) {
          float f = v[r] + bc + (biasRow ? biasRow[row + r] : 0.f);
          outBb[(size_t)(row + r) * N + col] = f2b(f);
        }
      } else {
        if (biasRow) {
          v[0] += biasRow[row]; v[1] += biasRow[row + 1];
          v[2] += biasRow[row + 2]; v[3] += biasRow[row + 3];
        }
        size_t o = (size_t)col * M + row;
        if constexpr (EPI == 2) {
          float* outFb = outF + (size_t)b * sOb;
          *(f32x4*)&outFb[o] = v;
        }
        u16x4 pk;
        pk[0] = f2b(v[0]); pk[1] = f2b(v[1]); pk[2] = f2b(v[2]); pk[3] = f2b(v[3]);
        *(u16x4*)&outBb[o] = pk;
      }
    }
  }
}

// ---------------- fused masked flash attention (8 waves, K-split 2) ----------------
// theta,phi: [B,N,C] bf16; gv: [B,C,N] bf16 (V^T); mm: [B,N] f32 binary
// Writes UNNORMALIZED partials per split s: Op_s[b][n][c] f32 and ml2[s][b][n] = (m, l).
// LDS layout (transposed-chunk, conflict-free):
//   Kt[p][slot][row]: slot = 16B col-chunk (0..31), row = key-local (0..63), el off = slot*512 + row*8
//   Vt[p][slot][c]  : slot = 16B key-chunk (0..7), c = channel (0..255), el off = slot*2048 + c*8
__launch_bounds__(512, 2)
__global__ void attn_k(const unsigned short* __restrict__ theta,
                       const unsigned short* __restrict__ phi,
                       const unsigned short* __restrict__ gv,
                       const float* __restrict__ mm,
                       float* __restrict__ Op0,
                       float* __restrict__ Op1,
                       float2* __restrict__ ml2) {
  int b = blockIdx.y;
  int s = blockIdx.z;
  int q0 = blockIdx.x * 128;
  int kbase = s * 2048;
  int tid = threadIdx.x, lane = tid & 63, wid = tid >> 6;
  int r16 = lane & 15, g4 = lane >> 4;
  const unsigned short* th = theta + (size_t)b * PB;
  const unsigned short* ph = phi + (size_t)b * PB;
  const unsigned short* gb = gv + (size_t)b * PB;

  __shared__ __align__(16) unsigned short Kt[2][16384];   // 2 x 32KB
  __shared__ __align__(16) unsigned short Vt[2][16384];   // 2 x 32KB
  __shared__ float mlds[2048];                            // 8KB (this split's mask)
  __shared__ __align__(16) unsigned short Plds[8][16][72];// 18KB

  for (int i = tid; i < 2048; i += 512) mlds[i] = mm[b * NPIX + kbase + i];

  // Q fragments (16 q-rows per wave), stay in registers
  int qrow = q0 + wid * 16 + r16;
  bf16x8 aq[8];
  #pragma unroll
  for (int ks = 0; ks < 8; ++ks)
    aq[ks] = *(const bf16x8*)(th + (size_t)qrow * CC + ks * 32 + 8 * g4);

  f32x4 O[16];
  #pragma unroll
  for (int cf = 0; cf < 16; ++cf) { O[cf][0] = 0.f; O[cf][1] = 0.f; O[cf][2] = 0.f; O[cf][3] = 0.f; }
  float mrow[4] = {-1e30f, -1e30f, -1e30f, -1e30f};
  float lrow[4] = {0.f, 0.f, 0.f, 0.f};

  bf16x8 kst[4], vst[4];
  // stage tile 0
  {
    int k0g = kbase;
    #pragma unroll
    for (int i = 0; i < 4; ++i) {
      int slot = wid * 4 + i;
      kst[i] = *(const bf16x8*)(ph + (size_t)(k0g + lane) * CC + slot * 8);
      vst[i] = *(const bf16x8*)(gb + (size_t)(i * 64 + lane) * NPIX + k0g + wid * 8);
    }
    #pragma unroll
    for (int i = 0; i < 4; ++i) {
      int slot = wid * 4 + i;
      *(bf16x8*)&Kt[0][slot * 512 + lane * 8] = kst[i];
      *(bf16x8*)&Vt[0][wid * 2048 + i * 512 + lane * 8] = vst[i];
    }
  }
  __syncthreads();

  #pragma unroll 1
  for (int t = 0; t < 32; ++t) {
    int p = t & 1;
    // T14: issue next tile's global loads EARLY (hide under compute)
    if (t < 31) {
      int k0g = kbase + (t + 1) * 64;
      #pragma unroll
      for (int i = 0; i < 4; ++i) {
        int slot = wid * 4 + i;
        kst[i] = *(const bf16x8*)(ph + (size_t)(k0g + lane) * CC + slot * 8);
        vst[i] = *(const bf16x8*)(gb + (size_t)(i * 64 + lane) * NPIX + k0g + wid * 8);
      }
    }
    // ---- QK^T from LDS ----
    f32x4 S[4];
    #pragma unroll
    for (int f = 0; f < 4; ++f) { S[f][0] = 0.f; S[f][1] = 0.f; S[f][2] = 0.f; S[f][3] = 0.f; }
    #pragma unroll
    for (int ks = 0; ks < 8; ++ks) {
      #pragma unroll
      for (int f = 0; f < 4; ++f) {
        bf16x8 bk = *(const bf16x8*)&Kt[p][(ks * 4 + g4) * 512 + (f * 16 + r16) * 8];
        S[f] = mfma16(aq[ks], bk, S[f]);
      }
    }
    // ---- masked online softmax ----
    float mk[4];
    #pragma unroll
    for (int f = 0; f < 4; ++f) mk[f] = mlds[t * 64 + f * 16 + r16];
    float scr[4];
    #pragma unroll
    for (int r = 0; r < 4; ++r) {
      float v = -1e30f;
      #pragma unroll
      for (int f = 0; f < 4; ++f) v = fmaxf(v, mk[f] > 0.f ? S[f][r] : -1e30f);
      v = fmaxf(v, __shfl_xor(v, 1));
      v = fmaxf(v, __shfl_xor(v, 2));
      v = fmaxf(v, __shfl_xor(v, 4));
      v = fmaxf(v, __shfl_xor(v, 8));
      float nm = fmaxf(mrow[r], v);
      scr[r] = __expf(mrow[r] - nm);
      mrow[r] = nm;
      lrow[r] *= scr[r];
    }
    float ps[4][4];
    float rsum[4] = {0.f, 0.f, 0.f, 0.f};
    #pragma unroll
    for (int f = 0; f < 4; ++f)
      #pragma unroll
      for (int r = 0; r < 4; ++r) {
        float pp = mk[f] > 0.f ? __expf(S[f][r] - mrow[r]) : 0.f;
        ps[f][r] = pp;
        rsum[r] += pp;
      }
    #pragma unroll
    for (int r = 0; r < 4; ++r) {
      float sm = rsum[r];
      sm += __shfl_xor(sm, 1);
      sm += __shfl_xor(sm, 2);
      sm += __shfl_xor(sm, 4);
      sm += __shfl_xor(sm, 8);
      lrow[r] += sm;
    }
    #pragma unroll
    for (int cf = 0; cf < 16; ++cf) {
      O[cf][0] *= scr[0]; O[cf][1] *= scr[1]; O[cf][2] *= scr[2]; O[cf][3] *= scr[3];
    }
    // ---- P relayout via per-wave LDS bounce ----
    #pragma unroll
    for (int f = 0; f < 4; ++f)
      #pragma unroll
      for (int r = 0; r < 4; ++r)
        Plds[wid][g4 * 4 + r][f * 16 + r16] = f2b(ps[f][r]);
    // ---- PV from LDS ----
    #pragma unroll
    for (int ks2 = 0; ks2 < 2; ++ks2) {
      bf16x8 ap = *(const bf16x8*)&Plds[wid][r16][ks2 * 32 + 8 * g4];
      #pragma unroll
      for (int cf = 0; cf < 16; ++cf) {
        bf16x8 bv = *(const bf16x8*)&Vt[p][(ks2 * 4 + g4) * 2048 + (cf * 16 + r16) * 8];
        O[cf] = mfma16(ap, bv, O[cf]);
      }
    }
    // T14: write staged regs into the idle buffer LATE, then one barrier
    if (t < 31) {
      #pragma unroll
      for (int i = 0; i < 4; ++i) {
        int slot = wid * 4 + i;
        *(bf16x8*)&Kt[p ^ 1][slot * 512 + lane * 8] = kst[i];
        *(bf16x8*)&Vt[p ^ 1][wid * 2048 + i * 512 + lane * 8] = vst[i];
      }
    }
    __syncthreads();
  }

  // ---- epilogue: unnormalized partial O (f32) + (m, l) per q-row ----
  float* Opb = (s ? Op1 : Op0) + (size_t)b * NPIX * CC;
  #pragma unroll
  for (int cf = 0; cf < 16; ++cf)
    #pragma unroll
    for (int r = 0; r < 4; ++r)
      Opb[(size_t)(q0 + wid * 16 + g4 * 4 + r) * CC + cf * 16 + r16] = O[cf][r];
  if (r16 == 0) {
    #pragma unroll
    for (int r = 0; r < 4; ++r)
      ml2[(size_t)(s * BB + b) * NPIX + q0 + wid * 16 + g4 * 4 + r] =
          make_float2(mrow[r], lrow[r]);
  }
}

// ---------------- combine the 2 K-split partials -> y bf16 [B,N,C] ----------------
__global__ void attn_combine_k(const float* __restrict__ Op0, const float* __restrict__ Op1,
                               const float2* __restrict__ ml2, unsigned short* __restrict__ y) {
  size_t e = ((size_t)blockIdx.x * 256 + threadIdx.x) * 8;   // element in [B*N*C)
  int bn = (int)(e >> 8);
  float2 a = ml2[bn];
  float2 c = ml2[16384 + bn];
  float M = fmaxf(a.x, c.x);
  float e0 = __expf(a.x - M), e1 = __expf(c.x - M);
  float L = a.y * e0 + c.y * e1;
  float sc = L > 1e-30f ? 1.f / L : 0.f;
  e0 *= sc; e1 *= sc;
  f32x4 p0 = *(const f32x4*)&Op0[e];
  f32x4 p1 = *(const f32x4*)&Op0[e + 4];
  f32x4 q0 = *(const f32x4*)&Op1[e];
  f32x4 q1 = *(const f32x4*)&Op1[e + 4];
  bf16x8 r;
  #pragma unroll
  for (int j = 0; j < 4; ++j) {
    r[j]     = (short)f2b(p0[j] * e0 + q0[j] * e1);
    r[4 + j] = (short)f2b(p1[j] * e0 + q1[j] * e1);
  }
  *(bf16x8*)&y[e] = r;
}

// ---------------- instance-norm stats ----------------
__global__ void in_stats_k(const unsigned short* __restrict__ v,
                           float* __restrict__ psum, float* __restrict__ psumsq) {
  int p = blockIdx.x;          // 32 pixel-chunks of 128
  int b = blockIdx.y;
  int c = threadIdx.x;
  const unsigned short* base = v + (size_t)b * PB + (size_t)p * 128 * CC + c;
  float s = 0.f, s2 = 0.f;
  for (int n = 0; n < 128; ++n) {
    float f = b2f(base[n * CC]);
    s += f; s2 += f * f;
  }
  int o = (p * BB + b) * CC + c;
  psum[o] = s; psumsq[o] = s2;
}

__global__ void in_finalize_k(const float* __restrict__ psum, const float* __restrict__ psumsq,
                              float* __restrict__ mu, float* __restrict__ rs) {
  int bc = blockIdx.x * 256 + threadIdx.x;   // 1024
  int b = bc >> 8, c = bc & 255;
  float s = 0.f, s2 = 0.f;
  for (int p = 0; p < 32; ++p) {
    s  += psum[(p * BB + b) * CC + c];
    s2 += psumsq[(p * BB + b) * CC + c];
  }
  float m_ = s * (1.f / 4096.f);
  float var = s2 * (1.f / 4096.f) - m_ * m_;
  var = var > 0.f ? var : 0.f;
  mu[bc] = m_;
  rs[bc] = rsqrtf(var + 1e-5f);
}

// ---------------- IN+ReLU apply ----------------
__global__ void normrelu_k(const unsigned short* __restrict__ src,
                           const float* __restrict__ mu, const float* __restrict__ rs,
                           unsigned short* __restrict__ dst) {
  size_t idx = (size_t)blockIdx.x * 256 + threadIdx.x;
  size_t e = idx * 8;
  if (e >= (size_t)BB * PB) return;
  int c = (int)(e & 255);
  int b = (int)(e >> 20);
  const float* mup = mu + b * 256 + c;
  const float* rsp = rs + b * 256 + c;
  bf16x8 v = *(const bf16x8*)(src + e);
  bf16x8 ov;
  #pragma unroll
  for (int j = 0; j < 8; ++j) {
    float f = (b2f((unsigned short)v[j]) - mup[j]) * rsp[j];
    ov[j] = (short)f2b(f > 0.f ? f : 0.f);
  }
  *(bf16x8*)(dst + e) = ov;
}

// ---------------- residual += IN(conv2), keep f32 + bf16 ----------------
__global__ void resupdate_k(const unsigned short* __restrict__ c2,
                            const float* __restrict__ mu, const float* __restrict__ rs,
                            float* __restrict__ r, unsigned short* __restrict__ rb) {
  size_t idx = (size_t)blockIdx.x * 256 + threadIdx.x;
  size_t e = idx * 8;
  if (e >= (size_t)BB * PB) return;
  int c = (int)(e & 255);
  int b = (int)(e >> 20);
  const float* mup = mu + b * 256 + c;
  const float* rsp = rs + b * 256 + c;
  bf16x8 v = *(const bf16x8*)(c2 + e);
  bf16x8 ov;
  #pragma unroll
  for (int j = 0; j < 8; ++j) {
    float f = r[e + j] + (b2f((unsigned short)v[j]) - mup[j]) * rsp[j];
    r[e + j] = f;
    ov[j] = (short)f2b(f);
  }
  *(bf16x8*)(rb + e) = ov;
}

// ---------------- final blend: out[b,c,n] = m*x + (1-m)*r3[b,n,c] ----------------
__global__ void final_blend_k(const float* __restrict__ x, const float* __restrict__ r,
                              const float* __restrict__ m, float* __restrict__ out) {
  __shared__ float T[64][65];
  int b = blockIdx.z;
  int n0 = blockIdx.x * 64, c0 = blockIdx.y * 64;
  int tx = threadIdx.x, ty = threadIdx.y;
  #pragma unroll
  for (int i = 0; i < 16; ++i) {
    int nl = ty + i * 4;
    T[nl][tx] = r[(size_t)b * PB + (size_t)(n0 + nl) * CC + c0 + tx];
  }
  __syncthreads();
  #pragma unroll
  for (int i = 0; i < 16; ++i) {
    int cl = ty + i * 4;
    int cg = c0 + cl, ng = n0 + tx;
    float mv = m[b * NPIX + ng];
    float xv = x[(size_t)b * PB + (size_t)cg * NPIX + ng];
    out[(size_t)b * PB + (size_t)cg * NPIX + ng] = mv * xv + (1.f - mv) * T[tx][cl];
  }
}

// ---------------- workspace layout (bytes) ----------------
#define OFF_M    0UL
#define OFF_XT   65536UL        // xT bf16 [B,N,C]; later reused as y
#define OFF_TH   8454144UL      // theta bf16 [B,N,C]; later reused as cbuf (c1/c2)
#define OFF_PH   16842752UL     // phi bf16 [B,N,C]; later reused as hbuf
#define OFF_G    25231360UL     // g bf16 [B,C,N]; later reused as rb
#define OFF_R    33619968UL     // residual f32 [B,N,C]; during attn = Opart split 0 (16MB)
#define OFF_W1   50397184UL     // 1x1 weights bf16: theta, phi, g, W (65536 each)
#define OFF_WK   50921472UL     // res conv weights bf16 [6][9][256][256]
#define OFF_MU   57999360UL
#define OFF_RS   58003456UL
#define OFF_PS   58007552UL
#define OFF_PS2  58138624UL
#define OFF_OP1  58269696UL     // attn partial split 1 f32 (16MB)
#define OFF_ML   75046912UL     // attn (m,l) float2 [2][B][N] (256KB)  -> top ~75.3MB

extern "C" void kernel_launch(void* const* d_in, const int* in_sizes, int n_in,
                              void* d_out, int out_size, void* d_ws, size_t ws_size,
                              hipStream_t stream) {
  const float* x       = (const float*)d_in[0];
  const float* maskp   = (const float*)d_in[1];
  const float* g_w     = (const float*)d_in[2];
  const float* g_b     = (const float*)d_in[3];
  const float* theta_w = (const float*)d_in[4];
  const float* theta_b = (const float*)d_in[5];
  const float* phi_w   = (const float*)d_in[6];
  const float* phi_b   = (const float*)d_in[7];
  const float* W_w     = (const float*)d_in[8];
  const float* W_b     = (const float*)d_in[9];
  const float* res_w1  = (const float*)d_in[10];
  const float* res_w2  = (const float*)d_in[12];
  float* out = (float*)d_out;
  char* ws = (char*)d_ws;

  float*          mbuf = (float*)(ws + OFF_M);
  unsigned short* xT   = (unsigned short*)(ws + OFF_XT);
  unsigned short* ybuf = (unsigned short*)(ws + OFF_XT);   // alias (xT dead after g-gemm)
  unsigned short* thb  = (unsigned short*)(ws + OFF_TH);
  unsigned short* cbuf = (unsigned short*)(ws + OFF_TH);   // alias (theta dead after attn)
  unsigned short* phb  = (unsigned short*)(ws + OFF_PH);
  unsigned short* hbuf = (unsigned short*)(ws + OFF_PH);   // alias (phi dead after attn)
  unsigned short* gbuf = (unsigned short*)(ws + OFF_G);
  unsigned short* rb   = (unsigned short*)(ws + OFF_G);    // alias (g dead after attn)
  float*          rbuf = (float*)(ws + OFF_R);
  float*          op0  = (float*)(ws + OFF_R);             // alias (rbuf dead until W_y gemm)
  float*          op1  = (float*)(ws + OFF_OP1);
  float2*         ml2  = (float2*)(ws + OFF_ML);
  unsigned short* thw  = (unsigned short*)(ws + OFF_W1);
  unsigned short* phw  = (unsigned short*)(ws + OFF_W1 + 131072);
  unsigned short* gww  = (unsigned short*)(ws + OFF_W1 + 262144);
  unsigned short* Www  = (unsigned short*)(ws + OFF_W1 + 393216);
  unsigned short* wkres= (unsigned short*)(ws + OFF_WK);
  float*          mu   = (float*)(ws + OFF_MU);
  float*          rs   = (float*)(ws + OFF_RS);
  float*          psum = (float*)(ws + OFF_PS);
  float*          psq  = (float*)(ws + OFF_PS2);

  // weight repacks + mask + x transpose
  repack_w1x1_k<<<256, 256, 0, stream>>>(theta_w, phi_w, g_w, W_w, thw);
  repack_res_k<<<6912, 256, 0, stream>>>(res_w1, res_w2, wkres);
  prep_mask_k<<<64, 256, 0, stream>>>(maskp, mbuf);
  transpose_x_k<<<dim3(64, 4, 4), dim3(64, 4), 0, stream>>>(x, xT);

  // theta = xT @ theta_w^T + b  -> [B,N,C]
  gemm_bt<0, false><<<dim3(4, 32, 4), 256, 0, stream>>>(
      xT, thw, nullptr, theta_b, nullptr, thb, 4096, 256, 256, (long)PB, 0L, (long)PB);
  // phi = xT @ phi_w^T + b -> [B,N,C]
  gemm_bt<0, false><<<dim3(4, 32, 4), 256, 0, stream>>>(
      xT, phw, nullptr, phi_b, nullptr, phb, 4096, 256, 256, (long)PB, 0L, (long)PB);
  // g = g_w @ xT^T + b -> [B,C,N]
  gemm_bt<0, false><<<dim3(64, 2, 4), 256, 0, stream>>>(
      gww, xT, g_b, nullptr, nullptr, gbuf, 256, 4096, 256, 0L, (long)PB, (long)PB);

  // flash attention partials (K-split 2) + combine -> y [B,N,C]
  attn_k<<<dim3(32, 4, 2), 512, 0, stream>>>(thb, phb, gbuf, mbuf, op0, op1, ml2);
  attn_combine_k<<<2048, 256, 0, stream>>>(op0, op1, ml2, ybuf);

  // W_y = W_w @ y^T + W_b -> residual f32 [B,N,C] + bf16 copy
  gemm_bt<2, false><<<dim3(64, 2, 4), 256, 0, stream>>>(
      Www, ybuf, W_b, nullptr, rbuf, rb, 256, 4096, 256, 0L, (long)PB, (long)PB);

  // 3 residual blocks
  for (int i = 0; i < 3; ++i) {
    gemm_bt<1, true><<<dim3(64, 2, 4), 256, 0, stream>>>(
        wkres + (size_t)(2 * i) * 589824, rb, nullptr, nullptr, nullptr, cbuf,
        256, 4096, 256, 0L, (long)PB, (long)PB);
    in_stats_k<<<dim3(32, 4), 256, 0, stream>>>(cbuf, psum, psq);
    in_finalize_k<<<4, 256, 0, stream>>>(psum, psq, mu, rs);
    normrelu_k<<<2048, 256, 0, stream>>>(cbuf, mu, rs, hbuf);
    gemm_bt<1, true><<<dim3(64, 2, 4), 256, 0, stream>>>(
        wkres + (size_t)(2 * i + 1) * 589824, hbuf, nullptr, nullptr, nullptr, cbuf,
        256, 4096, 256, 0L, (long)PB, (long)PB);
    in_stats_k<<<dim3(32, 4), 256, 0, stream>>>(cbuf, psum, psq);
    in_finalize_k<<<4, 256, 0, stream>>>(psum, psq, mu, rs);
    resupdate_k<<<2048, 256, 0, stream>>>(cbuf, mu, rs, rbuf, rb);
  }

  // final blend + transpose to [B,C,H,W]
  final_blend_k<<<dim3(64, 4, 4), dim3(64, 4), 0, stream>>>(x, rbuf, mbuf, out);
}

// Round 5
// 515.606 us; speedup vs baseline: 2.0879x; 1.2754x over previous
//
#include <hip/hip_runtime.h>

// Problem constants
#define BB   4
#define CC   256
#define NPIX 4096            // 64*64
#define PB   1048576         // per-batch elements: NPIX*CC
#define NTOT 16384           // B * NPIX (batch folded into GEMM N)

typedef __attribute__((ext_vector_type(8))) short bf16x8;
typedef __attribute__((ext_vector_type(4))) float f32x4;
typedef __attribute__((ext_vector_type(4))) unsigned short u16x4;

__device__ __forceinline__ unsigned short f2b(float f) {
  union { float f; unsigned u; } v; v.f = f;
  unsigned r = v.u + 0x7fffu + ((v.u >> 16) & 1u);
  return (unsigned short)(r >> 16);
}
__device__ __forceinline__ float b2f(unsigned short h) {
  union { unsigned u; float f; } v; v.u = ((unsigned)h) << 16;
  return v.f;
}
__device__ __forceinline__ f32x4 mfma16(bf16x8 a, bf16x8 b, f32x4 c) {
  return __builtin_amdgcn_mfma_f32_16x16x32_bf16(a, b, c, 0, 0, 0);
}
// async global->LDS, 16B per lane. LDS dst = wave-uniform base + lane*16 (linear).
__device__ __forceinline__ void gload_lds16(const unsigned short* g, unsigned short* l) {
  __builtin_amdgcn_global_load_lds(
      (const __attribute__((address_space(1))) unsigned int*)g,
      (__attribute__((address_space(3))) unsigned int*)l, 16, 0, 0);
}
// reflect-pad(1) pixel remap for 64x64 image
__device__ __forceinline__ int remap_px(int n, int dh, int dw) {
  int h = (n >> 6) + dh;
  int w = (n & 63) + dw;
  h = h < 0 ? 1 : (h > 63 ? 62 : h);
  w = w < 0 ? 1 : (w > 63 ? 62 : w);
  return (h << 6) | w;
}

// ---------------- weight / bias repack ----------------
__global__ void repack_w1x1_k(const float* __restrict__ tw, const float* __restrict__ pw,
                              const float* __restrict__ gw, const float* __restrict__ Ww,
                              unsigned short* __restrict__ dst) {
  int i = blockIdx.x * 256 + threadIdx.x;          // 65536 total
  dst[i]           = f2b(tw[i]);
  dst[65536 + i]   = f2b(pw[i]);
  dst[131072 + i]  = f2b(gw[i]);
  dst[196608 + i]  = f2b(Ww[i]);
}

__global__ void repack_bias_k(const float* __restrict__ tb, const float* __restrict__ pb,
                              const float* __restrict__ gb, const float* __restrict__ Wb,
                              float* __restrict__ bias) {
  int i = blockIdx.x * 256 + threadIdx.x;          // 1024
  float v;
  if (i < 256) v = tb[i];
  else if (i < 512) v = pb[i - 256];
  else if (i < 768) v = gb[i - 512];
  else v = Wb[i - 768];
  bias[i] = v;
}

__global__ void repack_res_k(const float* __restrict__ w1, const float* __restrict__ w2,
                             unsigned short* __restrict__ wk) {
  int idx = blockIdx.x * 256 + threadIdx.x;        // 3*256*256*9 = 1769472 total
  if (idx >= 1769472) return;
  int t = idx % 9;
  int rest = idx / 9;                              // (i*256+o)*256+c
  int c = rest & 255;
  int o = (rest >> 8) & 255;
  int i = rest >> 16;
  size_t d = (size_t)t * 65536 + o * 256 + c;      // [t][o][c] within one conv
  wk[(size_t)(2 * i)     * 589824 + d] = f2b(w1[idx]);
  wk[(size_t)(2 * i + 1) * 589824 + d] = f2b(w2[idx]);
}

// ---------------- mask prep ----------------
__global__ void prep_mask_k(const float* __restrict__ mask, float* __restrict__ m) {
  int idx = blockIdx.x * 256 + threadIdx.x;        // B*4096
  if (idx >= BB * NPIX) return;
  int b = idx >> 12, n = idx & 4095;
  int h = n >> 6, w = n & 63;
  const float* M = mask + b * 1024;
  float sh = 0.5f * h - 0.25f, sw = 0.5f * w - 0.25f;
  int h0 = (int)floorf(sh), w0 = (int)floorf(sw);
  float th = sh - h0, tw = sw - w0;
  int h0c = min(max(h0, 0), 31), h1c = min(max(h0 + 1, 0), 31);
  int w0c = min(max(w0, 0), 31), w1c = min(max(w0 + 1, 0), 31);
  float v = (1.f - th) * ((1.f - tw) * M[h0c * 32 + w0c] + tw * M[h0c * 32 + w1c])
          +        th  * ((1.f - tw) * M[h1c * 32 + w0c] + tw * M[h1c * 32 + w1c]);
  float inv = v > 0.f ? 0.f : 1.f;
  float tmp = 1.f - M[(h >> 1) * 32 + (w >> 1)];
  m[idx] = inv * tmp;                              // binary {0,1}
}

// ---------------- key compaction: scan + gathers ----------------
__global__ void mask_scan_k(const float* __restrict__ mbuf, int* __restrict__ ci,
                            int* __restrict__ kcount) {
  int b = blockIdx.x;
  int tid = threadIdx.x;                           // 256, 16 pix each
  __shared__ int sc[256];
  const float* mb = mbuf + b * 4096;
  int n0 = tid * 16, cnt = 0;
  float mv[16];
  #pragma unroll
  for (int i = 0; i < 16; ++i) { mv[i] = mb[n0 + i]; cnt += mv[i] > 0.f ? 1 : 0; }
  sc[tid] = cnt;
  __syncthreads();
  for (int off = 1; off < 256; off <<= 1) {
    int v = sc[tid];
    int u = tid >= off ? sc[tid - off] : 0;
    __syncthreads();
    sc[tid] = v + u;
    __syncthreads();
  }
  int base = sc[tid] - cnt;                        // exclusive prefix
  int* cib = ci + b * 4096;
  #pragma unroll
  for (int i = 0; i < 16; ++i)
    if (mv[i] > 0.f) cib[base++] = n0 + i;
  if (tid == 255) kcount[b] = sc[255];
}

__global__ void gather_phi_k(const unsigned short* __restrict__ phb, const int* __restrict__ ci,
                             const int* __restrict__ kcount, unsigned short* __restrict__ phic) {
  int b = blockIdx.y;
  int Kb = kcount[b];
  int pad = (Kb + 63) & ~63;
  int j = blockIdx.x * 8 + (threadIdx.x >> 5);
  int cl = threadIdx.x & 31;
  if (j >= pad) return;
  bf16x8 v;
  if (j < Kb) {
    v = *(const bf16x8*)(phb + (size_t)b * PB + (size_t)ci[b * 4096 + j] * 256 + cl * 8);
  } else {
    for (int t = 0; t < 8; ++t) v[t] = 0;
  }
  *(bf16x8*)(phic + (size_t)b * PB + (size_t)j * 256 + cl * 8) = v;
}

__global__ void gather_g_k(const unsigned short* __restrict__ gbuf, const int* __restrict__ ci,
                           const int* __restrict__ kcount, unsigned short* __restrict__ gc) {
  int b = blockIdx.z;
  int Kb = kcount[b];
  int pad = (Kb + 63) & ~63;
  int c = blockIdx.y;
  int j = blockIdx.x * 256 + threadIdx.x;
  if (j >= pad) return;
  unsigned short v = 0;
  if (j < Kb) v = gbuf[(size_t)c * NTOT + b * 4096 + ci[b * 4096 + j]];
  gc[(size_t)c * NTOT + b * 4096 + j] = v;
}

// ---------------- x transpose: [B,C,N] f32 -> [B,N,C] bf16 ----------------
__global__ void transpose_x_k(const float* __restrict__ x, unsigned short* __restrict__ xT) {
  __shared__ float T[64][65];
  int b = blockIdx.z;
  int n0 = blockIdx.x * 64, c0 = blockIdx.y * 64;
  int tx = threadIdx.x, ty = threadIdx.y;
  const float* xb = x + (size_t)b * PB;
  #pragma unroll
  for (int i = 0; i < 16; ++i) {
    int cl = ty + i * 4;
    T[cl][tx] = xb[(size_t)(c0 + cl) * NPIX + n0 + tx];
  }
  __syncthreads();
  unsigned short* ob = xT + (size_t)b * PB;
  #pragma unroll
  for (int i = 0; i < 16; ++i) {
    int nl = ty + i * 4;
    ob[(size_t)(n0 + nl) * CC + c0 + tx] = f2b(T[tx][nl]);
  }
}

// ---------------- weight-stationary GEMM: C[M,NTOT] = A[M,K] * Bact[NTOT,K]^T ----------------
// TM=128, TN=64, BK=64; global_load_lds staging; XOR-swizzled LDS (free 2-way conflicts);
// XCD-swizzled n-tiles. TAPS=9 adds reflect-pad conv remap on B rows.
// EPI 0: fused theta|phi|g (M=768): sec 0/1 -> [B,N,C] bf16 (+bias); sec 2 -> [C,NTOT] bf16 (+bias)
// EPI 1: bf16 [B,N,C] (convs, no bias)
// EPI 2: f32 [B,N,C] + bf16 copy (+bias)
template <int EPI, int TAPS>
__launch_bounds__(256, 2)
__global__ void gemm_w(const unsigned short* __restrict__ A,
                       const unsigned short* __restrict__ Bact,
                       const float* __restrict__ bias,
                       float* __restrict__ outF,
                       unsigned short* __restrict__ o0,
                       unsigned short* __restrict__ o1,
                       unsigned short* __restrict__ o2) {
  int m0 = blockIdx.y * 128;
  int bxs = (blockIdx.x & 7) * 32 + (blockIdx.x >> 3);   // XCD-chunked n-tiles
  int n0 = bxs * 64;
  int tid = threadIdx.x, lane = tid & 63, wid = tid >> 6;
  int wm = wid >> 1, wn = wid & 1;
  int r16 = lane & 15, g4 = lane >> 4;
  __shared__ __align__(16) unsigned short As[8192];   // [128 rows][128B] swizzled
  __shared__ __align__(16) unsigned short Bs[4096];   // [64 rows][128B] swizzled
  f32x4 acc[4][2] = {};
  // staging geometry: issue i covers LDS bytes L = tid*16 + i*4096
  int srow[4], scolel[4];
  #pragma unroll
  for (int i = 0; i < 4; ++i) {
    int L = tid * 16 + i * 4096;
    int row = L >> 7;
    srow[i] = row;
    scolel[i] = ((L & 127) ^ ((row & 7) << 4)) >> 1;   // pre-swizzled global col (elements)
  }
  // LDS read bases (row fixed per lane across the k-loop)
  int ra[4], qa[4];
  #pragma unroll
  for (int i = 0; i < 4; ++i) { int r = wm * 64 + i * 16 + r16; ra[i] = r * 128; qa[i] = r & 7; }
  int rbb[2], qb[2];
  #pragma unroll
  for (int j = 0; j < 2; ++j) { int c = wn * 32 + j * 16 + r16; rbb[j] = c * 128; qb[j] = c & 7; }

  const int nsteps = TAPS * 4;
  for (int st = 0; st < nsteps; ++st) {
    int tap = st >> 2;
    int k0 = (st & 3) * 64;
    const unsigned short* At = A + tap * 65536;
    __syncthreads();                       // prev-tile reads done before overwrite
    #pragma unroll
    for (int i = 0; i < 4; ++i)
      gload_lds16(At + (size_t)(m0 + srow[i]) * 256 + k0 + scolel[i],
                  &As[(tid * 16 + i * 4096) >> 1]);
    #pragma unroll
    for (int i = 0; i < 2; ++i) {
      int n = n0 + srow[i];
      int bsrc = n;
      if (TAPS == 9) bsrc = (n & ~4095) | remap_px(n & 4095, tap / 3 - 1, tap % 3 - 1);
      gload_lds16(Bact + (size_t)bsrc * 256 + k0 + scolel[i],
                  &Bs[(tid * 16 + i * 4096) >> 1]);
    }
    __syncthreads();                       // vmcnt drained by compiler before barrier
    #pragma unroll
    for (int kk = 0; kk < 2; ++kk) {
      bf16x8 af[4], bfv[2];
      #pragma unroll
      for (int i = 0; i < 4; ++i)
        af[i] = *(const bf16x8*)((const char*)As + ra[i] + (((kk * 4 + g4) ^ qa[i]) << 4));
      #pragma unroll
      for (int j = 0; j < 2; ++j)
        bfv[j] = *(const bf16x8*)((const char*)Bs + rbb[j] + (((kk * 4 + g4) ^ qb[j]) << 4));
      #pragma unroll
      for (int i = 0; i < 4; ++i)
        #pragma unroll
        for (int j = 0; j < 2; ++j)
          acc[i][j] = mfma16(af[i], bfv[j], acc[i][j]);
    }
  }
  // epilogue
  #pragma unroll
  for (int i = 0; i < 4; ++i) {
    int row = m0 + wm * 64 + i * 16 + g4 * 4;
    #pragma unroll
    for (int j = 0; j < 2; ++j) {
      int n = n0 + wn * 32 + j * 16 + r16;
      f32x4 v = acc[i][j];
      if constexpr (EPI == 0) {
        int sec = row >> 8;
        int ch = row & 255;
        if (sec < 2) {
          u16x4 pk;
          #pragma unroll
          for (int r = 0; r < 4; ++r) pk[r] = f2b(v[r] + bias[row + r]);
          *(u16x4*)((sec ? o1 : o0) + (size_t)n * 256 + ch) = pk;
        } else {
          #pragma unroll
          for (int r = 0; r < 4; ++r)
            o2[(size_t)(ch + r) * NTOT + n] = f2b(v[r] + bias[row + r]);
        }
      } else if constexpr (EPI == 1) {
        u16x4 pk;
        #pragma unroll
        for (int r = 0; r < 4; ++r) pk[r] = f2b(v[r]);
        *(u16x4*)(o0 + (size_t)n * 256 + row) = pk;
      } else {
        #pragma unroll
        for (int r = 0; r < 4; ++r) v[r] += bias[row + r];
        *(f32x4*)(outF + (size_t)n * 256 + row) = v;
        u16x4 pk;
        #pragma unroll
        for (int r = 0; r < 4; ++r) pk[r] = f2b(v[r]);
        *(u16x4*)(o0 + (size_t)n * 256 + row) = pk;
      }
    }
  }
}

// ---------------- fused masked flash attention over COMPACTED keys ----------------
// theta: [B,N,C] bf16; phic: [B,4096pad,C] bf16 (kept keys); gc: [C,NTOT] bf16 (kept keys per batch)
// kcount[b] = #kept keys. Writes unnormalized partials per split s + (m,l).
__launch_bounds__(512, 2)
__global__ void attn_k(const unsigned short* __restrict__ theta,
                       const unsigned short* __restrict__ phic,
                       const unsigned short* __restrict__ gc,
                       const int* __restrict__ kcount,
                       float* __restrict__ Op0,
                       float* __restrict__ Op1,
                       float2* __restrict__ ml2) {
  int f = blockIdx.x;                 // 256 blocks; XCD = f%8 -> one (b,s) per XCD
  int b = (f & 7) >> 1;
  int s = f & 1;
  int q0 = (f >> 3) * 128;
  int tid = threadIdx.x, lane = tid & 63, wid = tid >> 6;
  int r16 = lane & 15, g4 = lane >> 4;
  const unsigned short* th = theta + (size_t)b * PB;
  const unsigned short* phb = phic + (size_t)b * PB;

  int Kb = kcount[b];
  int nt = (Kb + 63) >> 6;
  int h = (nt + 1) >> 1;
  int t0 = s * h, t1 = min(nt, t0 + h);

  __shared__ __align__(16) unsigned short Kt[2][16384];   // 2 x 32KB
  __shared__ __align__(16) unsigned short Vt[2][16384];   // 2 x 32KB
  __shared__ __align__(16) unsigned short Plds[8][16][72];

  // Q fragments (16 q-rows per wave)
  int qrow = q0 + wid * 16 + r16;
  bf16x8 aq[8];
  #pragma unroll
  for (int ks = 0; ks < 8; ++ks)
    aq[ks] = *(const bf16x8*)(th + (size_t)qrow * CC + ks * 32 + 8 * g4);

  f32x4 O[16];
  #pragma unroll
  for (int cf = 0; cf < 16; ++cf) { O[cf][0] = 0.f; O[cf][1] = 0.f; O[cf][2] = 0.f; O[cf][3] = 0.f; }
  float mrow[4] = {-1e30f, -1e30f, -1e30f, -1e30f};
  float lrow[4] = {0.f, 0.f, 0.f, 0.f};

  bf16x8 kst[4], vst[4];
  if (t0 < t1) {
    int k0g = t0 * 64;
    #pragma unroll
    for (int i = 0; i < 4; ++i) {
      int slot = wid * 4 + i;
      kst[i] = *(const bf16x8*)(phb + (size_t)(k0g + lane) * CC + slot * 8);
      vst[i] = *(const bf16x8*)(gc + (size_t)(i * 64 + lane) * NTOT + b * 4096 + k0g + wid * 8);
    }
    #pragma unroll
    for (int i = 0; i < 4; ++i) {
      int slot = wid * 4 + i;
      *(bf16x8*)&Kt[0][slot * 512 + lane * 8] = kst[i];
      *(bf16x8*)&Vt[0][wid * 2048 + i * 512 + lane * 8] = vst[i];
    }
  }
  __syncthreads();

  #pragma unroll 1
  for (int t = t0; t < t1; ++t) {
    int p = (t - t0) & 1;
    if (t + 1 < t1) {
      int k0g = (t + 1) * 64;
      #pragma unroll
      for (int i = 0; i < 4; ++i) {
        int slot = wid * 4 + i;
        kst[i] = *(const bf16x8*)(phb + (size_t)(k0g + lane) * CC + slot * 8);
        vst[i] = *(const bf16x8*)(gc + (size_t)(i * 64 + lane) * NTOT + b * 4096 + k0g + wid * 8);
      }
    }
    // ---- QK^T ----
    f32x4 S[4];
    #pragma unroll
    for (int ff = 0; ff < 4; ++ff) { S[ff][0] = 0.f; S[ff][1] = 0.f; S[ff][2] = 0.f; S[ff][3] = 0.f; }
    #pragma unroll
    for (int ks = 0; ks < 8; ++ks) {
      #pragma unroll
      for (int ff = 0; ff < 4; ++ff) {
        bf16x8 bk = *(const bf16x8*)&Kt[p][(ks * 4 + g4) * 512 + (ff * 16 + r16) * 8];
        S[ff] = mfma16(aq[ks], bk, S[ff]);
      }
    }
    // ---- online softmax (validity: key index < Kb) ----
    bool mk[4];
    #pragma unroll
    for (int ff = 0; ff < 4; ++ff) mk[ff] = (t * 64 + ff * 16 + r16) < Kb;
    float scr[4];
    #pragma unroll
    for (int r = 0; r < 4; ++r) {
      float v = -1e30f;
      #pragma unroll
      for (int ff = 0; ff < 4; ++ff) v = fmaxf(v, mk[ff] ? S[ff][r] : -1e30f);
      v = fmaxf(v, __shfl_xor(v, 1));
      v = fmaxf(v, __shfl_xor(v, 2));
      v = fmaxf(v, __shfl_xor(v, 4));
      v = fmaxf(v, __shfl_xor(v, 8));
      float nm = fmaxf(mrow[r], v);
      scr[r] = __expf(mrow[r] - nm);
      mrow[r] = nm;
      lrow[r] *= scr[r];
    }
    float ps[4][4];
    float rsum[4] = {0.f, 0.f, 0.f, 0.f};
    #pragma unroll
    for (int ff = 0; ff < 4; ++ff)
      #pragma unroll
      for (int r = 0; r < 4; ++r) {
        float pp = mk[ff] ? __expf(S[ff][r] - mrow[r]) : 0.f;
        ps[ff][r] = pp;
        rsum[r] += pp;
      }
    #pragma unroll
    for (int r = 0; r < 4; ++r) {
      float sm = rsum[r];
      sm += __shfl_xor(sm, 1);
      sm += __shfl_xor(sm, 2);
      sm += __shfl_xor(sm, 4);
      sm += __shfl_xor(sm, 8);
      lrow[r] += sm;
    }
    #pragma unroll
    for (int cf = 0; cf < 16; ++cf) {
      O[cf][0] *= scr[0]; O[cf][1] *= scr[1]; O[cf][2] *= scr[2]; O[cf][3] *= scr[3];
    }
    // ---- P relayout via per-wave LDS bounce ----
    #pragma unroll
    for (int ff = 0; ff < 4; ++ff)
      #pragma unroll
      for (int r = 0; r < 4; ++r)
        Plds[wid][g4 * 4 + r][ff * 16 + r16] = f2b(ps[ff][r]);
    // ---- PV ----
    #pragma unroll
    for (int ks2 = 0; ks2 < 2; ++ks2) {
      bf16x8 ap = *(const bf16x8*)&Plds[wid][r16][ks2 * 32 + 8 * g4];
      #pragma unroll
      for (int cf = 0; cf < 16; ++cf) {
        bf16x8 bv = *(const bf16x8*)&Vt[p][(ks2 * 4 + g4) * 2048 + (cf * 16 + r16) * 8];
        O[cf] = mfma16(ap, bv, O[cf]);
      }
    }
    if (t + 1 < t1) {
      #pragma unroll
      for (int i = 0; i < 4; ++i) {
        int slot = wid * 4 + i;
        *(bf16x8*)&Kt[p ^ 1][slot * 512 + lane * 8] = kst[i];
        *(bf16x8*)&Vt[p ^ 1][wid * 2048 + i * 512 + lane * 8] = vst[i];
      }
    }
    __syncthreads();
  }

  // ---- epilogue: unnormalized partial O (f32) + (m, l) per q-row ----
  float* Opb = (s ? Op1 : Op0) + (size_t)b * NPIX * CC;
  #pragma unroll
  for (int cf = 0; cf < 16; ++cf)
    #pragma unroll
    for (int r = 0; r < 4; ++r)
      Opb[(size_t)(q0 + wid * 16 + g4 * 4 + r) * CC + cf * 16 + r16] = O[cf][r];
  if (r16 == 0) {
    #pragma unroll
    for (int r = 0; r < 4; ++r)
      ml2[(size_t)(s * BB + b) * NPIX + q0 + wid * 16 + g4 * 4 + r] =
          make_float2(mrow[r], lrow[r]);
  }
}

// ---------------- combine the 2 K-split partials -> y bf16 [B,N,C] ----------------
__global__ void attn_combine_k(const float* __restrict__ Op0, const float* __restrict__ Op1,
                               const float2* __restrict__ ml2, unsigned short* __restrict__ y) {
  size_t e = ((size_t)blockIdx.x * 256 + threadIdx.x) * 8;
  int bn = (int)(e >> 8);
  float2 a = ml2[bn];
  float2 c = ml2[16384 + bn];
  float M = fmaxf(a.x, c.x);
  float e0 = __expf(a.x - M), e1 = __expf(c.x - M);
  float L = a.y * e0 + c.y * e1;
  float sc = L > 1e-30f ? 1.f / L : 0.f;
  e0 *= sc; e1 *= sc;
  f32x4 p0 = *(const f32x4*)&Op0[e];
  f32x4 p1 = *(const f32x4*)&Op0[e + 4];
  f32x4 q0 = *(const f32x4*)&Op1[e];
  f32x4 q1 = *(const f32x4*)&Op1[e + 4];
  bf16x8 r;
  #pragma unroll
  for (int j = 0; j < 4; ++j) {
    r[j]     = (short)f2b(p0[j] * e0 + q0[j] * e1);
    r[4 + j] = (short)f2b(p1[j] * e0 + q1[j] * e1);
  }
  *(bf16x8*)&y[e] = r;
}

// ---------------- instance-norm stats ----------------
__global__ void in_stats_k(const unsigned short* __restrict__ v,
                           float* __restrict__ psum, float* __restrict__ psumsq) {
  int p = blockIdx.x;
  int b = blockIdx.y;
  int c = threadIdx.x;
  const unsigned short* base = v + (size_t)b * PB + (size_t)p * 128 * CC + c;
  float s = 0.f, s2 = 0.f;
  for (int n = 0; n < 128; ++n) {
    float f = b2f(base[n * CC]);
    s += f; s2 += f * f;
  }
  int o = (p * BB + b) * CC + c;
  psum[o] = s; psumsq[o] = s2;
}

__global__ void in_finalize_k(const float* __restrict__ psum, const float* __restrict__ psumsq,
                              float* __restrict__ mu, float* __restrict__ rs) {
  int bc = blockIdx.x * 256 + threadIdx.x;
  int b = bc >> 8, c = bc & 255;
  float s = 0.f, s2 = 0.f;
  for (int p = 0; p < 32; ++p) {
    s  += psum[(p * BB + b) * CC + c];
    s2 += psumsq[(p * BB + b) * CC + c];
  }
  float m_ = s * (1.f / 4096.f);
  float var = s2 * (1.f / 4096.f) - m_ * m_;
  var = var > 0.f ? var : 0.f;
  mu[bc] = m_;
  rs[bc] = rsqrtf(var + 1e-5f);
}

// ---------------- IN+ReLU apply ----------------
__global__ void normrelu_k(const unsigned short* __restrict__ src,
                           const float* __restrict__ mu, const float* __restrict__ rs,
                           unsigned short* __restrict__ dst) {
  size_t idx = (size_t)blockIdx.x * 256 + threadIdx.x;
  size_t e = idx * 8;
  if (e >= (size_t)BB * PB) return;
  int c = (int)(e & 255);
  int b = (int)(e >> 20);
  const float* mup = mu + b * 256 + c;
  const float* rsp = rs + b * 256 + c;
  bf16x8 v = *(const bf16x8*)(src + e);
  bf16x8 ov;
  #pragma unroll
  for (int j = 0; j < 8; ++j) {
    float f = (b2f((unsigned short)v[j]) - mup[j]) * rsp[j];
    ov[j] = (short)f2b(f > 0.f ? f : 0.f);
  }
  *(bf16x8*)(dst + e) = ov;
}

// ---------------- residual += IN(conv2), keep f32 + bf16 ----------------
__global__ void resupdate_k(const unsigned short* __restrict__ c2,
                            const float* __restrict__ mu, const float* __restrict__ rs,
                            float* __restrict__ r, unsigned short* __restrict__ rb) {
  size_t idx = (size_t)blockIdx.x * 256 + threadIdx.x;
  size_t e = idx * 8;
  if (e >= (size_t)BB * PB) return;
  int c = (int)(e & 255);
  int b = (int)(e >> 20);
  const float* mup = mu + b * 256 + c;
  const float* rsp = rs + b * 256 + c;
  bf16x8 v = *(const bf16x8*)(c2 + e);
  bf16x8 ov;
  #pragma unroll
  for (int j = 0; j < 8; ++j) {
    float f = r[e + j] + (b2f((unsigned short)v[j]) - mup[j]) * rsp[j];
    r[e + j] = f;
    ov[j] = (short)f2b(f);
  }
  *(bf16x8*)(rb + e) = ov;
}

// ---------------- final blend ----------------
__global__ void final_blend_k(const float* __restrict__ x, const float* __restrict__ r,
                              const float* __restrict__ m, float* __restrict__ out) {
  __shared__ float T[64][65];
  int b = blockIdx.z;
  int n0 = blockIdx.x * 64, c0 = blockIdx.y * 64;
  int tx = threadIdx.x, ty = threadIdx.y;
  #pragma unroll
  for (int i = 0; i < 16; ++i) {
    int nl = ty + i * 4;
    T[nl][tx] = r[(size_t)b * PB + (size_t)(n0 + nl) * CC + c0 + tx];
  }
  __syncthreads();
  #pragma unroll
  for (int i = 0; i < 16; ++i) {
    int cl = ty + i * 4;
    int cg = c0 + cl, ng = n0 + tx;
    float mv = m[b * NPIX + ng];
    float xv = x[(size_t)b * PB + (size_t)cg * NPIX + ng];
    out[(size_t)b * PB + (size_t)cg * NPIX + ng] = mv * xv + (1.f - mv) * T[tx][cl];
  }
}

// ---------------- workspace layout (bytes) ----------------
#define OFF_M    0UL            // mask f32 [B,N] 64KB
#define OFF_XT   65536UL        // 8MB: xT -> phic (gather) -> ybuf (combine)
#define OFF_TH   8454144UL      // 8MB: theta [B,N,C] -> cbuf
#define OFF_PH   16842752UL     // 8MB: phi [B,N,C] -> gc -> hbuf
#define OFF_G    25231360UL     // 8MB: g [C,NTOT] -> rb
#define OFF_R    33619968UL     // 16MB: op0 -> rbuf f32 [B,N,C]
#define OFF_W1   50397184UL     // 1x1 weights bf16 stacked: theta|phi|g|W
#define OFF_WK   50921472UL     // res conv weights bf16 [6][9][256][256]
#define OFF_MU   57999360UL
#define OFF_RS   58003456UL
#define OFF_PS   58007552UL
#define OFF_PS2  58138624UL
#define OFF_OP1  58269696UL     // attn partial split 1 f32 (16MB)
#define OFF_ML   75046912UL     // (m,l) float2 [2][B][N] (256KB)
#define OFF_CI   75309056UL     // compact indices int [B][4096] (64KB)
#define OFF_KC   75374592UL     // kcount int[4]
#define OFF_BIAS 75374848UL     // stacked bias f32 [1024]

extern "C" void kernel_launch(void* const* d_in, const int* in_sizes, int n_in,
                              void* d_out, int out_size, void* d_ws, size_t ws_size,
                              hipStream_t stream) {
  const float* x       = (const float*)d_in[0];
  const float* maskp   = (const float*)d_in[1];
  const float* g_w     = (const float*)d_in[2];
  const float* g_b     = (const float*)d_in[3];
  const float* theta_w = (const float*)d_in[4];
  const float* theta_b = (const float*)d_in[5];
  const float* phi_w   = (const float*)d_in[6];
  const float* phi_b   = (const float*)d_in[7];
  const float* W_w     = (const float*)d_in[8];
  const float* W_b     = (const float*)d_in[9];
  const float* res_w1  = (const float*)d_in[10];
  const float* res_w2  = (const float*)d_in[12];
  float* out = (float*)d_out;
  char* ws = (char*)d_ws;

  float*          mbuf = (float*)(ws + OFF_M);
  unsigned short* xT   = (unsigned short*)(ws + OFF_XT);
  unsigned short* phic = (unsigned short*)(ws + OFF_XT);   // alias: xT dead after TPG gemm
  unsigned short* ybuf = (unsigned short*)(ws + OFF_XT);   // alias: phic dead after attn
  unsigned short* thb  = (unsigned short*)(ws + OFF_TH);
  unsigned short* cbuf = (unsigned short*)(ws + OFF_TH);
  unsigned short* phb  = (unsigned short*)(ws + OFF_PH);
  unsigned short* gc   = (unsigned short*)(ws + OFF_PH);   // alias: phb dead after gather_phi
  unsigned short* hbuf = (unsigned short*)(ws + OFF_PH);   // alias: gc dead after attn
  unsigned short* gbuf = (unsigned short*)(ws + OFF_G);
  unsigned short* rb   = (unsigned short*)(ws + OFF_G);    // alias: gbuf dead after gather_g
  float*          rbuf = (float*)(ws + OFF_R);
  float*          op0  = (float*)(ws + OFF_R);             // alias: dead before W_y gemm
  float*          op1  = (float*)(ws + OFF_OP1);
  float2*         ml2  = (float2*)(ws + OFF_ML);
  int*            ci   = (int*)(ws + OFF_CI);
  int*            kc   = (int*)(ws + OFF_KC);
  float*          biasS= (float*)(ws + OFF_BIAS);
  unsigned short* thw  = (unsigned short*)(ws + OFF_W1);   // stacked theta|phi|g|W
  unsigned short* Www  = (unsigned short*)(ws + OFF_W1 + 393216);
  unsigned short* wkres= (unsigned short*)(ws + OFF_WK);
  float*          mu   = (float*)(ws + OFF_MU);
  float*          rs   = (float*)(ws + OFF_RS);
  float*          psum = (float*)(ws + OFF_PS);
  float*          psq  = (float*)(ws + OFF_PS2);

  // prep
  repack_w1x1_k<<<256, 256, 0, stream>>>(theta_w, phi_w, g_w, W_w, thw);
  repack_res_k<<<6912, 256, 0, stream>>>(res_w1, res_w2, wkres);
  repack_bias_k<<<4, 256, 0, stream>>>(theta_b, phi_b, g_b, W_b, biasS);
  prep_mask_k<<<64, 256, 0, stream>>>(maskp, mbuf);
  transpose_x_k<<<dim3(64, 4, 4), dim3(64, 4), 0, stream>>>(x, xT);

  // fused theta|phi|g projection (M=768)
  gemm_w<0, 1><<<dim3(256, 6), 256, 0, stream>>>(thw, xT, biasS, nullptr, thb, phb, gbuf);

  // key compaction
  mask_scan_k<<<4, 256, 0, stream>>>(mbuf, ci, kc);
  gather_phi_k<<<dim3(512, 4), 256, 0, stream>>>(phb, ci, kc, phic);
  gather_g_k<<<dim3(16, 256, 4), 256, 0, stream>>>(gbuf, ci, kc, gc);

  // flash attention over compacted keys (K-split 2) + combine
  attn_k<<<256, 512, 0, stream>>>(thb, phic, gc, kc, op0, op1, ml2);
  attn_combine_k<<<2048, 256, 0, stream>>>(op0, op1, ml2, ybuf);

  // W_y projection -> residual f32 + bf16
  gemm_w<2, 1><<<dim3(256, 2), 256, 0, stream>>>(Www, ybuf, biasS + 768, rbuf, rb, nullptr, nullptr);

  // 3 residual blocks
  for (int i = 0; i < 3; ++i) {
    gemm_w<1, 9><<<dim3(256, 2), 256, 0, stream>>>(
        wkres + (size_t)(2 * i) * 589824, rb, nullptr, nullptr, cbuf, nullptr, nullptr);
    in_stats_k<<<dim3(32, 4), 256, 0, stream>>>(cbuf, psum, psq);
    in_finalize_k<<<4, 256, 0, stream>>>(psum, psq, mu, rs);
    normrelu_k<<<2048, 256, 0, stream>>>(cbuf, mu, rs, hbuf);
    gemm_w<1, 9><<<dim3(256, 2), 256, 0, stream>>>(
        wkres + (size_t)(2 * i + 1) * 589824, hbuf, nullptr, nullptr, cbuf, nullptr, nullptr);
    in_stats_k<<<dim3(32, 4), 256, 0, stream>>>(cbuf, psum, psq);
    in_finalize_k<<<4, 256, 0, stream>>>(psum, psq, mu, rs);
    resupdate_k<<<2048, 256, 0, stream>>>(cbuf, mu, rs, rbuf, rb);
  }

  // final blend + transpose to [B,C,H,W]
  final_blend_k<<<dim3(64, 4, 4), dim3(64, 4), 0, stream>>>(x, rbuf, mbuf, out);
}